// Round 4
// baseline (410.216 us; speedup 1.0000x reference)
//
#include <hip/hip_runtime.h>

// NW=32 wavelets, N=M=1024.
#define NPOINTS 1048576ULL
#define NWV 32

typedef _Float16 h8 __attribute__((ext_vector_type(8)));
typedef _Float16 h4 __attribute__((ext_vector_type(4)));
typedef _Float16 h2 __attribute__((ext_vector_type(2)));
typedef float f32x4 __attribute__((ext_vector_type(4)));

// Scaling plan: rowfft applies NO ifft scale (T rms ~45, f16-safe).
// colfft output conv' = 2^20 * conv_true; mod' = sqrt(xx+yy+1e-8*2^40).
// Final reduce multiplies by 2^-20 (einsum 1/(N*M)) * 2^-40 (mod'^2) = 2^-60.

// ---------------------------------------------------------------------------
// Compacted inverse-FFT twiddles, W_L^pos = exp(+2*pi*i*pos/L), L = 2^(hb+1).
// Stage hb (half = 2^hb): base = 1024 - 2^(hb+1), size 2^hb, hb = 9..2.
// ---------------------------------------------------------------------------
__global__ void k_init_tw(float2* __restrict__ tw) {
    int hb   = 9 - blockIdx.x;              // 9..2
    int cnt  = 1 << hb;
    int base = 1024 - (2 << hb);
    for (int pos = threadIdx.x; pos < cnt; pos += 256) {
        double ang = 6.283185307179586232 * (double)pos / (double)(2 << hb);
        tw[base + pos] = make_float2((float)cos(ang), (float)sin(ang));
    }
}

__device__ __forceinline__ void bf(float2& a, float2& b, float2 w) {
    float sx = a.x + b.x, sy = a.y + b.y;
    float dx = a.x - b.x, dy = a.y - b.y;
    a = make_float2(sx, sy);
    b = make_float2(dx * w.x - dy * w.y, dx * w.y + dy * w.x);
}

// One 1024-pt inverse DIF FFT per 64-lane wave. ex = this wave's PRIVATE
// 1028-entry h2 plane (intra-wave exchange only -> NO barrier needed; DS ops
// of one wave complete in order and the compiler orders may-alias LDS).
// In: X[k] = elem l+64k. Out: bit-reversed-order slots i = 64*(l>>2)+(l&3)+4j
// (consistent spatial permutation, Gram-safe).
__device__ __forceinline__ void wave_fft(float2* X, int l,
    const float2* __restrict__ twl, h2* __restrict__ ex)
{
    #pragma unroll
    for (int st = 0; st < 4; ++st) {        // half = 512,256,128,64
        const int step = 8 >> st;
        const float2* tb = twl + (1024 - (1024 >> st));
        #pragma unroll
        for (int g = 0; g < 16; g += 2 * step)
            #pragma unroll
            for (int c = 0; c < step; ++c)
                bf(X[g + c], X[g + c + step], tb[l + 64 * c]);
    }
    #pragma unroll
    for (int k = 0; k < 16; ++k) {          // XOR-swizzled h2 exchange
        int ph = 64 * k + (l ^ (k << 2));
        ex[ph] = h2{(_Float16)X[k].x, (_Float16)X[k].y};
    }
    const int b = l >> 2, q = l & 3;
    float2 Y[16];
    #pragma unroll
    for (int j = 0; j < 16; ++j) {
        int ph = 64 * b + (((q + 4 * j) ^ (b << 2)) & 63);
        h2 v = ex[ph];
        Y[j] = make_float2((float)v.x, (float)v.y);
    }
    #pragma unroll
    for (int st = 0; st < 4; ++st) {        // half = 32,16,8,4
        const int step = 8 >> st;
        const float2* tb = twl + (1024 - (64 >> st));
        #pragma unroll
        for (int g = 0; g < 16; g += 2 * step)
            #pragma unroll
            for (int c = 0; c < step; ++c)
                bf(Y[g + c], Y[g + c + step], tb[q + 4 * c]);
    }
    #pragma unroll
    for (int j = 0; j < 16; ++j) {          // half=2: lane^2, tw 1 / +i
        float ox = __shfl_xor(Y[j].x, 2);
        float oy = __shfl_xor(Y[j].y, 2);
        if ((l & 2) == 0) { Y[j].x += ox; Y[j].y += oy; }
        else {
            float dx = ox - Y[j].x, dy = oy - Y[j].y;
            Y[j] = (l & 1) ? make_float2(-dy, dx) : make_float2(dx, dy);
        }
    }
    #pragma unroll
    for (int j = 0; j < 16; ++j) {          // half=1: lane^1, tw 1
        float ox = __shfl_xor(Y[j].x, 1);
        float oy = __shfl_xor(Y[j].y, 1);
        if ((l & 1) == 0) { Y[j].x += ox; Y[j].y += oy; }
        else { Y[j].x = ox - Y[j].x; Y[j].y = oy - Y[j].y; }
    }
    #pragma unroll
    for (int j = 0; j < 16; ++j) X[j] = Y[j];
}

// ---------------------------------------------------------------------------
// Pass A: 8 waves/block = 8 rows of one wavelet. Pointwise complex multiply
// (unscaled), wave FFT, restage to h2 planes, block transpose, write T[c][n]
// column-major f16 (h4 = 2 complex per store).
// ---------------------------------------------------------------------------
__global__ __launch_bounds__(512, 6) void k_rowfft(
    const float2* __restrict__ xhat, const float* __restrict__ pre,
    const float* __restrict__ pim, const float2* __restrict__ twg,
    _Float16* __restrict__ T, int wbase)
{
    __shared__ h2     ex[8 * 1028];   // 8 per-row planes, stride 1028 (bank-spread)
    __shared__ float2 twl[1020];
    const int t  = threadIdx.x;
    const int wv = t >> 6, l = t & 63;
    const int n  = blockIdx.x * 8 + wv;
    const int wl = blockIdx.y, w = wbase + wl;
    for (int i = t; i < 1020; i += 512) twl[i] = twg[i];
    h2* exw = ex + wv * 1028;

    const float2* xr  = xhat + (size_t)n * 1024;
    const float*  prr = pre + (size_t)w * NPOINTS + (size_t)n * 1024;
    const float*  pir = pim + (size_t)w * NPOINTS + (size_t)n * 1024;
    float2 X[16];
    #pragma unroll
    for (int k = 0; k < 16; ++k) {
        float2 x = xr[l + 64 * k];
        float  a = prr[l + 64 * k], bb = pir[l + 64 * k];
        X[k] = make_float2(x.x * a - x.y * bb, x.y * a + x.x * bb);
    }
    __syncthreads();                       // twiddles ready
    wave_fft(X, l, twl, exw);

    // Restage outputs (slot i = 64b+q+4j) into this row's plane for transpose.
    const int b = l >> 2, q = l & 3;
    #pragma unroll
    for (int j = 0; j < 16; ++j) {
        int ph = 64 * b + (((q + 4 * j) ^ (b << 2)) & 63);
        exw[ph] = h2{(_Float16)X[j].x, (_Float16)X[j].y};
    }
    __syncthreads();
    // Emit T[c][n0..n0+7]: thread t -> c = v*128 + (t>>2), rows r2, r2+1.
    _Float16* Tw = T + (size_t)wl * NPOINTS * 2;
    const int n0 = blockIdx.x * 8;
    const int u = t >> 2, r2 = (t & 3) << 1;
    #pragma unroll
    for (int v = 0; v < 8; ++v) {
        int c  = v * 128 + u;
        int cb = c >> 6, low = c & 63;
        int ph = (cb << 6) + ((low ^ (cb << 2)) & 63);
        h2 v0 = ex[r2 * 1028 + ph];
        h2 v1 = ex[(r2 + 1) * 1028 + ph];
        h4 val = {v0.x, v0.y, v1.x, v1.y};
        *(h4*)&Tw[((size_t)c * 1024 + (size_t)(n0 + r2)) * 2] = val;
    }
}

// ---------------------------------------------------------------------------
// Pass B: 8 waves/block = 8 columns. Coalesced h2 column reads, wave FFT,
// mod' = sqrt(xx+yy+1e-8*2^40) stored f16 (packed h2). One barrier total.
// ---------------------------------------------------------------------------
__global__ __launch_bounds__(512, 6) void k_colfft(
    const _Float16* __restrict__ T, const float2* __restrict__ twg,
    _Float16* __restrict__ modb, int wbase)
{
    __shared__ h2     ex[8 * 1028];
    __shared__ float2 twl[1020];
    const int t  = threadIdx.x;
    const int wv = t >> 6, l = t & 63;
    const int c  = blockIdx.x * 8 + wv;
    const int wl = blockIdx.y, w = wbase + wl;
    for (int i = t; i < 1020; i += 512) twl[i] = twg[i];
    h2* exw = ex + wv * 1028;

    const _Float16* Tc = T + ((size_t)wl * NPOINTS + (size_t)c * 1024) * 2;
    float2 X[16];
    #pragma unroll
    for (int k = 0; k < 16; ++k) {
        h2 v = *(const h2*)&Tc[2 * (64 * k + l)];
        X[k] = make_float2((float)v.x, (float)v.y);
    }
    __syncthreads();                       // twiddles ready
    wave_fft(X, l, twl, exw);

    _Float16* mo = modb + (size_t)w * NPOINTS + (size_t)c * 1024;
    const float epsp = 1.09951162778e4f;   // 1e-8 * 2^40
    #pragma unroll
    for (int q = 0; q < 8; ++q) {
        float m0 = sqrtf(X[2*q].x * X[2*q].x + X[2*q].y * X[2*q].y + epsp);
        float m1 = sqrtf(X[2*q+1].x * X[2*q+1].x + X[2*q+1].y * X[2*q+1].y + epsp);
        *(h2*)&mo[2 * (q * 64 + l)] = h2{(_Float16)m0, (_Float16)m1};
    }
}

// ---------------------------------------------------------------------------
// Pass C: Gram partials via MFMA (unchanged math). Block = 2048 points;
// c00/c01/c11 quadrants, 2048 partial rows.
// ---------------------------------------------------------------------------
__global__ __launch_bounds__(256) void k_gram(
    const _Float16* __restrict__ modb, float* __restrict__ part)
{
    __shared__ _Float16 tile[32][520];
    const int t = threadIdx.x;
    const int l = t & 63, wv = t >> 6;
    f32x4 c00 = {0.f,0.f,0.f,0.f}, c01 = {0.f,0.f,0.f,0.f}, c11 = {0.f,0.f,0.f,0.f};
    const size_t pbase = (size_t)blockIdx.x * 2048;

    for (int tt = 0; tt < 4; ++tt) {
        __syncthreads();
        size_t p0 = pbase + (size_t)tt * 512;
        #pragma unroll
        for (int i = 0; i < 8; ++i) {
            int w = i * 4 + wv;
            *(h8*)&tile[w][(size_t)(l * 8)] =
                *(const h8*)&modb[((size_t)w << 20) + p0 + (size_t)(l * 8)];
        }
        __syncthreads();
        #pragma unroll
        for (int s = 0; s < 4; ++s) {
            int k0 = (s * 4 + wv) * 32 + ((l >> 4) * 8);
            h8 a0 = *(const h8*)&tile[l & 15][k0];
            h8 a1 = *(const h8*)&tile[16 + (l & 15)][k0];
            c00 = __builtin_amdgcn_mfma_f32_16x16x32_f16(a0, a0, c00, 0, 0, 0);
            c01 = __builtin_amdgcn_mfma_f32_16x16x32_f16(a0, a1, c01, 0, 0, 0);
            c11 = __builtin_amdgcn_mfma_f32_16x16x32_f16(a1, a1, c11, 0, 0, 0);
        }
    }
    const int row = (blockIdx.x << 2) | wv;     // 2048 partial rows
    float* pr = part + ((size_t)row << 10);
    #pragma unroll
    for (int r = 0; r < 4; ++r) {
        int i = (l >> 4) * 4 + r;    // C/D: col = l&15, row = (l>>4)*4+r
        int j = l & 15;
        pr[i * 32 + j]             = c00[r];
        pr[i * 32 + 16 + j]        = c01[r];
        pr[(16 + i) * 32 + 16 + j] = c11[r];
    }
}

// ---------------------------------------------------------------------------
// Pass D: parallel reduce of part[2048][1024]. 64 blocks x 16 slots;
// 16 chunks of 128 rows per slot, LDS combine. Scale 2^-60.
// ---------------------------------------------------------------------------
__global__ __launch_bounds__(256) void k_reduce(
    const float* __restrict__ part, float* __restrict__ out)
{
    __shared__ float red[16][17];
    const int t = threadIdx.x;
    const int sl    = t & 15;              // slot within block
    const int chunk = t >> 4;              // 0..15
    const int slot  = blockIdx.x * 16 + sl;
    float v = 0.0f;
    const int r0 = chunk * 128;
    for (int i = 0; i < 128; ++i)
        v += part[((size_t)(r0 + i) << 10) + slot];
    red[chunk][sl] = v;
    __syncthreads();
    if (t < 16) {
        float s = 0.0f;
        #pragma unroll
        for (int cch = 0; cch < 16; ++cch) s += red[cch][t];
        int sq = blockIdx.x * 16 + t;
        int i = sq >> 5, j = sq & 31;
        if (j >= i) {
            int q = 32 * i - (i * (i - 1)) / 2 + (j - i);
            if (q < 527) out[q] = s * 8.6736173798840355e-19f;   // 2^-60
        }
    }
}

// ---------------------------------------------------------------------------
extern "C" void kernel_launch(void* const* d_in, const int* in_sizes, int n_in,
                              void* d_out, int out_size, void* d_ws, size_t ws_size,
                              hipStream_t stream) {
    (void)in_sizes; (void)n_in; (void)out_size;
    const float2* xhat = (const float2*)d_in[0];
    const float*  pre  = (const float*)d_in[1];
    const float*  pim  = (const float*)d_in[2];
    float* out = (float*)d_out;

    char* ws = (char*)d_ws;
    float2*    tw   = (float2*)ws;                                  // 64 KB slot
    _Float16*  modb = (_Float16*)(ws + 65536);                      // 64 MB
    float*     part = (float*)(ws + 65536 + NWV * NPOINTS * 2ULL);  // 8 MB
    size_t     Toff = 65536 + NWV * NPOINTS * 2ULL + 2048ULL * 1024ULL * 4ULL;
    _Float16*  T    = (_Float16*)(ws + Toff);

    // T (f16) batched over wavelets; WB=8 -> 32 MB, L3-resident.
    int WB = 1;
    const int cands[4] = {8, 4, 2, 1};
    for (int c = 0; c < 4; ++c)
        if (Toff + (size_t)cands[c] * NPOINTS * 4ULL <= ws_size) { WB = cands[c]; break; }

    hipLaunchKernelGGL(k_init_tw, dim3(8), dim3(256), 0, stream, tw);
    for (int wb = 0; wb < NWV; wb += WB) {
        hipLaunchKernelGGL(k_rowfft, dim3(128, WB), dim3(512), 0, stream,
                           xhat, pre, pim, (const float2*)tw, T, wb);
        hipLaunchKernelGGL(k_colfft, dim3(128, WB), dim3(512), 0, stream,
                           (const _Float16*)T, (const float2*)tw, modb, wb);
    }
    hipLaunchKernelGGL(k_gram, dim3(512), dim3(256), 0, stream,
                       (const _Float16*)modb, part);
    hipLaunchKernelGGL(k_reduce, dim3(64), dim3(256), 0, stream,
                       (const float*)part, out);
}

// Round 5
// 279.275 us; speedup vs baseline: 1.4689x; 1.4689x over previous
//
#include <hip/hip_runtime.h>

// NW=32 wavelets, N=M=1024.
#define NPOINTS 1048576ULL
#define NWV 32

typedef _Float16 h8 __attribute__((ext_vector_type(8)));
typedef _Float16 h4 __attribute__((ext_vector_type(4)));
typedef _Float16 h2 __attribute__((ext_vector_type(2)));
typedef float f32x4 __attribute__((ext_vector_type(4)));

// Scaling plan: rowfft applies NO ifft scale (T rms ~45, f16-safe).
// colfft output conv' = 2^20 * conv_true; mod' = sqrt(xx+yy+1e-8*2^40).
// Final reduce multiplies by 2^-20 (einsum 1/(N*M)) * 2^-40 (mod'^2) = 2^-60.

// ---------------------------------------------------------------------------
// Compacted inverse-FFT twiddles, W_L^pos = exp(+2*pi*i*pos/L), L = 2^(hb+1).
// Stage hb (half = 2^hb): base = 1024 - 2^(hb+1), size 2^hb, hb = 9..2.
// ---------------------------------------------------------------------------
__global__ void k_init_tw(float2* __restrict__ tw) {
    int hb   = 9 - blockIdx.x;              // 9..2
    int cnt  = 1 << hb;
    int base = 1024 - (2 << hb);
    for (int pos = threadIdx.x; pos < cnt; pos += 256) {
        double ang = 6.283185307179586232 * (double)pos / (double)(2 << hb);
        tw[base + pos] = make_float2((float)cos(ang), (float)sin(ang));
    }
}

__device__ __forceinline__ void bf(float2& a, float2& b, float2 w) {
    float sx = a.x + b.x, sy = a.y + b.y;
    float dx = a.x - b.x, dy = a.y - b.y;
    a = make_float2(sx, sy);
    b = make_float2(dx * w.x - dy * w.y, dx * w.y + dy * w.x);
}

// One 1024-pt inverse DIF FFT per 64-lane wave. ex = this wave's PRIVATE
// 1028-entry h2 plane (intra-wave exchange only -> no barrier; the compiler
// orders may-alias DS ops within a wave via lgkmcnt).
// In: X[k] = elem l+64k. Out: bit-reversed-order slots i = 64*(l>>2)+(l&3)+4j
// (consistent spatial permutation, Gram-safe).
__device__ __forceinline__ void wave_fft(float2* X, int l,
    const float2* __restrict__ twl, h2* __restrict__ ex)
{
    #pragma unroll
    for (int st = 0; st < 4; ++st) {        // half = 512,256,128,64
        const int step = 8 >> st;
        const float2* tb = twl + (1024 - (1024 >> st));
        #pragma unroll
        for (int g = 0; g < 16; g += 2 * step)
            #pragma unroll
            for (int c = 0; c < step; ++c)
                bf(X[g + c], X[g + c + step], tb[l + 64 * c]);
    }
    #pragma unroll
    for (int k = 0; k < 16; ++k) {          // XOR-swizzled h2 exchange
        int ph = 64 * k + (l ^ (k << 2));
        ex[ph] = h2{(_Float16)X[k].x, (_Float16)X[k].y};
    }
    const int b = l >> 2, q = l & 3;
    float2 Y[16];
    #pragma unroll
    for (int j = 0; j < 16; ++j) {
        int ph = 64 * b + (((q + 4 * j) ^ (b << 2)) & 63);
        h2 v = ex[ph];
        Y[j] = make_float2((float)v.x, (float)v.y);
    }
    #pragma unroll
    for (int st = 0; st < 4; ++st) {        // half = 32,16,8,4
        const int step = 8 >> st;
        const float2* tb = twl + (1024 - (64 >> st));
        #pragma unroll
        for (int g = 0; g < 16; g += 2 * step)
            #pragma unroll
            for (int c = 0; c < step; ++c)
                bf(Y[g + c], Y[g + c + step], tb[q + 4 * c]);
    }
    #pragma unroll
    for (int j = 0; j < 16; ++j) {          // half=2: lane^2, tw 1 / +i
        float ox = __shfl_xor(Y[j].x, 2);
        float oy = __shfl_xor(Y[j].y, 2);
        if ((l & 2) == 0) { Y[j].x += ox; Y[j].y += oy; }
        else {
            float dx = ox - Y[j].x, dy = oy - Y[j].y;
            Y[j] = (l & 1) ? make_float2(-dy, dx) : make_float2(dx, dy);
        }
    }
    #pragma unroll
    for (int j = 0; j < 16; ++j) {          // half=1: lane^1, tw 1
        float ox = __shfl_xor(Y[j].x, 1);
        float oy = __shfl_xor(Y[j].y, 1);
        if ((l & 1) == 0) { Y[j].x += ox; Y[j].y += oy; }
        else { Y[j].x = ox - Y[j].x; Y[j].y = oy - Y[j].y; }
    }
    #pragma unroll
    for (int j = 0; j < 16; ++j) X[j] = Y[j];
}

// ---------------------------------------------------------------------------
// Pass A: 8 waves/block = 8 rows of one wavelet. Pointwise complex multiply
// (unscaled), wave FFT, restage to h2 planes, block transpose, write T[c][n]
// column-major f16 (h4 = 2 complex per store).
// __launch_bounds__(512,4): VGPR cap 128 — the register FFT needs ~90 VGPRs;
// (512,6) forced a 40-VGPR spill catastrophe (round 4: VALUBusy 11%).
// ---------------------------------------------------------------------------
__global__ __launch_bounds__(512, 4) void k_rowfft(
    const float2* __restrict__ xhat, const float* __restrict__ pre,
    const float* __restrict__ pim, const float2* __restrict__ twg,
    _Float16* __restrict__ T, int wbase)
{
    __shared__ h2     ex[8 * 1028];   // 8 per-row planes, stride 1028
    __shared__ float2 twl[1020];
    const int t  = threadIdx.x;
    const int wv = t >> 6, l = t & 63;
    const int n  = blockIdx.x * 8 + wv;
    const int wl = blockIdx.y, w = wbase + wl;
    for (int i = t; i < 1020; i += 512) twl[i] = twg[i];
    h2* exw = ex + wv * 1028;

    const float2* xr  = xhat + (size_t)n * 1024;
    const float*  prr = pre + (size_t)w * NPOINTS + (size_t)n * 1024;
    const float*  pir = pim + (size_t)w * NPOINTS + (size_t)n * 1024;
    float2 X[16];
    #pragma unroll
    for (int k = 0; k < 16; ++k) {
        float2 x = xr[l + 64 * k];
        float  a = prr[l + 64 * k], bb = pir[l + 64 * k];
        X[k] = make_float2(x.x * a - x.y * bb, x.y * a + x.x * bb);
    }
    __syncthreads();                       // twiddles ready
    wave_fft(X, l, twl, exw);

    // Restage outputs (slot i = 64b+q+4j) into this row's plane for transpose.
    const int b = l >> 2, q = l & 3;
    #pragma unroll
    for (int j = 0; j < 16; ++j) {
        int ph = 64 * b + (((q + 4 * j) ^ (b << 2)) & 63);
        exw[ph] = h2{(_Float16)X[j].x, (_Float16)X[j].y};
    }
    __syncthreads();
    // Emit T[c][n0..n0+7]: thread t -> c = v*128 + (t>>2), rows r2, r2+1.
    _Float16* Tw = T + (size_t)wl * NPOINTS * 2;
    const int n0 = blockIdx.x * 8;
    const int u = t >> 2, r2 = (t & 3) << 1;
    #pragma unroll
    for (int v = 0; v < 8; ++v) {
        int c  = v * 128 + u;
        int cb = c >> 6, low = c & 63;
        int ph = (cb << 6) + ((low ^ (cb << 2)) & 63);
        h2 v0 = ex[r2 * 1028 + ph];
        h2 v1 = ex[(r2 + 1) * 1028 + ph];
        h4 val = {v0.x, v0.y, v1.x, v1.y};
        *(h4*)&Tw[((size_t)c * 1024 + (size_t)(n0 + r2)) * 2] = val;
    }
}

// ---------------------------------------------------------------------------
// Pass B: 8 waves/block = 8 columns. Coalesced h2 column reads, wave FFT,
// mod' = sqrt(xx+yy+1e-8*2^40) stored f16 (packed h2). One barrier total.
// ---------------------------------------------------------------------------
__global__ __launch_bounds__(512, 4) void k_colfft(
    const _Float16* __restrict__ T, const float2* __restrict__ twg,
    _Float16* __restrict__ modb, int wbase)
{
    __shared__ h2     ex[8 * 1028];
    __shared__ float2 twl[1020];
    const int t  = threadIdx.x;
    const int wv = t >> 6, l = t & 63;
    const int c  = blockIdx.x * 8 + wv;
    const int wl = blockIdx.y, w = wbase + wl;
    for (int i = t; i < 1020; i += 512) twl[i] = twg[i];
    h2* exw = ex + wv * 1028;

    const _Float16* Tc = T + ((size_t)wl * NPOINTS + (size_t)c * 1024) * 2;
    float2 X[16];
    #pragma unroll
    for (int k = 0; k < 16; ++k) {
        h2 v = *(const h2*)&Tc[2 * (64 * k + l)];
        X[k] = make_float2((float)v.x, (float)v.y);
    }
    __syncthreads();                       // twiddles ready
    wave_fft(X, l, twl, exw);

    _Float16* mo = modb + (size_t)w * NPOINTS + (size_t)c * 1024;
    const float epsp = 1.09951162778e4f;   // 1e-8 * 2^40
    #pragma unroll
    for (int q = 0; q < 8; ++q) {
        float m0 = sqrtf(X[2*q].x * X[2*q].x + X[2*q].y * X[2*q].y + epsp);
        float m1 = sqrtf(X[2*q+1].x * X[2*q+1].x + X[2*q+1].y * X[2*q+1].y + epsp);
        *(h2*)&mo[2 * (q * 64 + l)] = h2{(_Float16)m0, (_Float16)m1};
    }
}

// ---------------------------------------------------------------------------
// Pass C: Gram partials via MFMA. Block = 2048 points; c00/c01/c11 quadrants,
// 2048 partial rows (c10 = c01^T never read).
// ---------------------------------------------------------------------------
__global__ __launch_bounds__(256) void k_gram(
    const _Float16* __restrict__ modb, float* __restrict__ part)
{
    __shared__ _Float16 tile[32][520];
    const int t = threadIdx.x;
    const int l = t & 63, wv = t >> 6;
    f32x4 c00 = {0.f,0.f,0.f,0.f}, c01 = {0.f,0.f,0.f,0.f}, c11 = {0.f,0.f,0.f,0.f};
    const size_t pbase = (size_t)blockIdx.x * 2048;

    for (int tt = 0; tt < 4; ++tt) {
        __syncthreads();
        size_t p0 = pbase + (size_t)tt * 512;
        #pragma unroll
        for (int i = 0; i < 8; ++i) {
            int w = i * 4 + wv;
            *(h8*)&tile[w][(size_t)(l * 8)] =
                *(const h8*)&modb[((size_t)w << 20) + p0 + (size_t)(l * 8)];
        }
        __syncthreads();
        #pragma unroll
        for (int s = 0; s < 4; ++s) {
            int k0 = (s * 4 + wv) * 32 + ((l >> 4) * 8);
            h8 a0 = *(const h8*)&tile[l & 15][k0];
            h8 a1 = *(const h8*)&tile[16 + (l & 15)][k0];
            c00 = __builtin_amdgcn_mfma_f32_16x16x32_f16(a0, a0, c00, 0, 0, 0);
            c01 = __builtin_amdgcn_mfma_f32_16x16x32_f16(a0, a1, c01, 0, 0, 0);
            c11 = __builtin_amdgcn_mfma_f32_16x16x32_f16(a1, a1, c11, 0, 0, 0);
        }
    }
    const int row = (blockIdx.x << 2) | wv;     // 2048 partial rows
    float* pr = part + ((size_t)row << 10);
    #pragma unroll
    for (int r = 0; r < 4; ++r) {
        int i = (l >> 4) * 4 + r;    // C/D: col = l&15, row = (l>>4)*4+r
        int j = l & 15;
        pr[i * 32 + j]             = c00[r];
        pr[i * 32 + 16 + j]        = c01[r];
        pr[(16 + i) * 32 + 16 + j] = c11[r];
    }
}

// ---------------------------------------------------------------------------
// Pass D: parallel reduce of part[2048][1024]. 64 blocks x 16 slots;
// 16 chunks of 128 rows per slot, LDS combine. Scale 2^-60.
// ---------------------------------------------------------------------------
__global__ __launch_bounds__(256) void k_reduce(
    const float* __restrict__ part, float* __restrict__ out)
{
    __shared__ float red[16][17];
    const int t = threadIdx.x;
    const int sl    = t & 15;              // slot within block
    const int chunk = t >> 4;              // 0..15
    const int slot  = blockIdx.x * 16 + sl;
    float v = 0.0f;
    const int r0 = chunk * 128;
    for (int i = 0; i < 128; ++i)
        v += part[((size_t)(r0 + i) << 10) + slot];
    red[chunk][sl] = v;
    __syncthreads();
    if (t < 16) {
        float s = 0.0f;
        #pragma unroll
        for (int cch = 0; cch < 16; ++cch) s += red[cch][t];
        int sq = blockIdx.x * 16 + t;
        int i = sq >> 5, j = sq & 31;
        if (j >= i) {
            int q = 32 * i - (i * (i - 1)) / 2 + (j - i);
            if (q < 527) out[q] = s * 8.6736173798840355e-19f;   // 2^-60
        }
    }
}

// ---------------------------------------------------------------------------
extern "C" void kernel_launch(void* const* d_in, const int* in_sizes, int n_in,
                              void* d_out, int out_size, void* d_ws, size_t ws_size,
                              hipStream_t stream) {
    (void)in_sizes; (void)n_in; (void)out_size;
    const float2* xhat = (const float2*)d_in[0];
    const float*  pre  = (const float*)d_in[1];
    const float*  pim  = (const float*)d_in[2];
    float* out = (float*)d_out;

    char* ws = (char*)d_ws;
    float2*    tw   = (float2*)ws;                                  // 64 KB slot
    _Float16*  modb = (_Float16*)(ws + 65536);                      // 64 MB
    float*     part = (float*)(ws + 65536 + NWV * NPOINTS * 2ULL);  // 8 MB
    size_t     Toff = 65536 + NWV * NPOINTS * 2ULL + 2048ULL * 1024ULL * 4ULL;
    _Float16*  T    = (_Float16*)(ws + Toff);

    // T (f16) batched over wavelets; WB=8 -> 32 MB, L3-resident.
    int WB = 1;
    const int cands[4] = {8, 4, 2, 1};
    for (int c = 0; c < 4; ++c)
        if (Toff + (size_t)cands[c] * NPOINTS * 4ULL <= ws_size) { WB = cands[c]; break; }

    hipLaunchKernelGGL(k_init_tw, dim3(8), dim3(256), 0, stream, tw);
    for (int wb = 0; wb < NWV; wb += WB) {
        hipLaunchKernelGGL(k_rowfft, dim3(128, WB), dim3(512), 0, stream,
                           xhat, pre, pim, (const float2*)tw, T, wb);
        hipLaunchKernelGGL(k_colfft, dim3(128, WB), dim3(512), 0, stream,
                           (const _Float16*)T, (const float2*)tw, modb, wb);
    }
    hipLaunchKernelGGL(k_gram, dim3(512), dim3(256), 0, stream,
                       (const _Float16*)modb, part);
    hipLaunchKernelGGL(k_reduce, dim3(64), dim3(256), 0, stream,
                       (const float*)part, out);
}